// Round 2
// baseline (1093.523 us; speedup 1.0000x reference)
//
#include <hip/hip_runtime.h>

// B=1024 queries, M=262144 bank rows, D=512, all unit vectors:
// min_dist[b] = sqrt(max(2 - 2*max_m dot(xhat_b, y_m), 1e-12))
//
// R2: 32x32x16 MFMA (2x FLOP per LDS byte), CM=64 -> 70.6KB LDS -> 2 wg/CU
// (occupancy 12%->24%), 64 q-cols/wave. Target ~200us for main kernel.

#define B_Q    1024
#define M_BANK 262144
#define DIM    512
#define CM     64          // bank rows in LDS per chunk
#define LDA    520         // padded stride (bf16): 1040B = 16*65 -> balanced quad-bank groups
#define NWG    512
#define CHUNKS 8           // 512 wgs * 8 chunks * 64 rows = 262144

typedef __attribute__((ext_vector_type(8)))  short short8;
typedef __attribute__((ext_vector_type(16))) float f32x16;

__device__ inline unsigned short f2bf(float f) {
  union { float f; unsigned u; } x; x.f = f;
  unsigned r = x.u + 0x7FFFu + ((x.u >> 16) & 1u);   // RNE
  return (unsigned short)(r >> 16);
}

// ---------- Kernel 1: normalize queries -> bf16 ----------
__global__ void normq_kernel(const float* __restrict__ X, unsigned short* __restrict__ Qn) {
  const int b = blockIdx.x;
  const int lane = threadIdx.x;  // 64
  const float4* row = (const float4*)(X + (size_t)b * DIM);
  float4 v0 = row[lane];
  float4 v1 = row[lane + 64];
  float ss = v0.x*v0.x + v0.y*v0.y + v0.z*v0.z + v0.w*v0.w
           + v1.x*v1.x + v1.y*v1.y + v1.z*v1.z + v1.w*v1.w;
  #pragma unroll
  for (int o = 32; o >= 1; o >>= 1) ss += __shfl_xor(ss, o);
  const float inv = 1.0f / sqrtf(ss);
  unsigned short* dst = Qn + (size_t)b * DIM;
  ushort4 o0 = make_ushort4(f2bf(v0.x*inv), f2bf(v0.y*inv), f2bf(v0.z*inv), f2bf(v0.w*inv));
  ushort4 o1 = make_ushort4(f2bf(v1.x*inv), f2bf(v1.y*inv), f2bf(v1.z*inv), f2bf(v1.w*inv));
  ((ushort4*)dst)[lane]      = o0;
  ((ushort4*)dst)[lane + 64] = o1;
}

// ---------- Kernel 2: GEMM (32x32x16 bf16 MFMA) + row-max ----------
// wg = 256 threads (4 waves), 2 wg/CU. Wave w owns q-cols [bt*256 + w*64, +64).
// A (bank chunk, 64 rows) LDS-resident bf16; B-frags from global Qn (L2-hot).
// MFMA A-frag: m = lane&31, k = (lane>>5)*8 + j.  B-frag: n = lane&31, same k.
// C/D: col(q) = lane&31, row spread over 16 regs + lane>>5 (max-reduced anyway).
__global__ __launch_bounds__(256, 2)
void patch_main(const float* __restrict__ bank, const unsigned short* __restrict__ Qn,
                float* __restrict__ partial) {
  __shared__ unsigned short bankT[CM * LDA];   // 66560 B
  __shared__ float runMax[B_Q];                // 4096 B   (70656 B total -> 2 wg/CU)

  const int tid  = threadIdx.x;
  const int lane = tid & 63;
  const int wave = tid >> 6;
  const int half = lane >> 5;   // k-half selector
  const int l32  = lane & 31;

  for (int i = tid; i < B_Q; i += 256) runMax[i] = -2.0f;

  const size_t mBase = (size_t)blockIdx.x * (CM * CHUNKS);

  for (int c = 0; c < CHUNKS; ++c) {
    __syncthreads();  // prior chunk's A-frag reads done before overwrite (covers init too)

    // ---- stage 64x512 fp32 -> bf16 LDS: 8192 float4, 32 per thread, coalesced ----
    const float4* src = (const float4*)(bank + (mBase + (size_t)c * CM) * DIM);
    #pragma unroll 8
    for (int p = 0; p < 32; ++p) {
      int f4 = p * 256 + tid;            // 0..8191
      float4 v = src[f4];
      int row = f4 >> 7;                 // /128 (512 floats = 128 float4 per row)
      int col = (f4 & 127) << 2;
      ushort4 o = make_ushort4(f2bf(v.x), f2bf(v.y), f2bf(v.z), f2bf(v.w));
      *(ushort4*)(bankT + row * LDA + col) = o;
    }
    __syncthreads();

    // ---- 4 passes of 256 queries; wave handles 64 q via 2 B-frags ----
    for (int bt = 0; bt < 4; ++bt) {
      f32x16 acc[2][2];                  // [a-frag(32 rows)][b-frag(32 q)]
      #pragma unroll
      for (int i = 0; i < 2; ++i)
        #pragma unroll
        for (int j = 0; j < 2; ++j)
          #pragma unroll
          for (int e = 0; e < 16; ++e) acc[i][j][e] = 0.0f;

      const int qb = bt * 256 + wave * 64;
      const unsigned short* qptr = Qn + (size_t)(qb + l32) * DIM + half * 8;
      const unsigned short* aptr = bankT + l32 * LDA + half * 8;

      #pragma unroll 4
      for (int ks = 0; ks < 32; ++ks) {  // k-step = 16
        const int k0 = ks * 16;
        short8 a0 = *(const short8*)(aptr + k0);
        short8 a1 = *(const short8*)(aptr + 32 * LDA + k0);
        short8 b0 = *(const short8*)(qptr + k0);
        short8 b1 = *(const short8*)(qptr + 32 * DIM + k0);
        acc[0][0] = __builtin_amdgcn_mfma_f32_32x32x16_bf16(a0, b0, acc[0][0], 0, 0, 0);
        acc[0][1] = __builtin_amdgcn_mfma_f32_32x32x16_bf16(a0, b1, acc[0][1], 0, 0, 0);
        acc[1][0] = __builtin_amdgcn_mfma_f32_32x32x16_bf16(a1, b0, acc[1][0], 0, 0, 0);
        acc[1][1] = __builtin_amdgcn_mfma_f32_32x32x16_bf16(a1, b1, acc[1][1], 0, 0, 0);
      }

      // max over all bank rows: all 16 regs, both a-frags, then lane^32 (same col)
      #pragma unroll
      for (int bf = 0; bf < 2; ++bf) {
        float mx = -2.0f;
        #pragma unroll
        for (int af = 0; af < 2; ++af)
          #pragma unroll
          for (int e = 0; e < 16; ++e) mx = fmaxf(mx, acc[af][bf][e]);
        mx = fmaxf(mx, __shfl_xor(mx, 32));
        if (lane < 32) {   // wave-exclusive q columns: no atomics
          int q = qb + bf * 32 + lane;
          runMax[q] = fmaxf(runMax[q], mx);
        }
      }
    }
  }

  __syncthreads();
  for (int i = tid; i < B_Q; i += 256)
    partial[(size_t)blockIdx.x * B_Q + i] = runMax[i];
}

// ---------- Kernel 3: reduce 512 partials, convert to distance ----------
__global__ void finalize_kernel(const float* __restrict__ partial, float* __restrict__ out) {
  const int b = blockIdx.x;      // 1024
  const int lane = threadIdx.x;  // 64
  float m = -2.0f;
  #pragma unroll
  for (int r = 0; r < NWG / 64; ++r)
    m = fmaxf(m, partial[(size_t)(r * 64 + lane) * B_Q + b]);
  #pragma unroll
  for (int o = 32; o >= 1; o >>= 1) m = fmaxf(m, __shfl_xor(m, o));
  if (lane == 0) out[b] = sqrtf(fmaxf(2.0f - 2.0f * m, 1e-12f));
}

extern "C" void kernel_launch(void* const* d_in, const int* in_sizes, int n_in,
                              void* d_out, int out_size, void* d_ws, size_t ws_size,
                              hipStream_t stream) {
  const float* feats = (const float*)d_in[0];   // [1024, 512] fp32
  const float* bank  = (const float*)d_in[1];   // [262144, 512] fp32, pre-normalized
  float* out = (float*)d_out;                   // [1024] fp32

  unsigned short* Qn = (unsigned short*)d_ws;                      // 1 MB bf16 queries
  float* partial = (float*)((char*)d_ws + (size_t)B_Q * DIM * 2);  // 2 MB partial maxes

  normq_kernel<<<B_Q, 64, 0, stream>>>(feats, Qn);
  patch_main<<<NWG, 256, 0, stream>>>(bank, Qn, partial);
  finalize_kernel<<<B_Q, 64, 0, stream>>>(partial, out);
}